// Round 5
// baseline (966.874 us; speedup 1.0000x reference)
//
#include <hip/hip_runtime.h>

#define N_NODES 100000
#define N_EDGES 1600000
#define N_GRAPHS 256
#define CH 128
#define OUT_CH 64
#define CAP 64       // per-node neighbor capacity; P(Poisson(16) > 64) ~ 1e-20
#define PLANE_U32 (N_NODES * 8)   // uints per 16-channel slice plane (32 B/node)
#define PLANE_U16 (N_NODES * 16)  // ushorts per slice plane

typedef __attribute__((ext_vector_type(8))) short bf16x8;
typedef __attribute__((ext_vector_type(4))) float f32x4;
typedef unsigned short ushort_t;
typedef unsigned int uint_t;

static __device__ inline ushort_t f2bf(float f) {
    uint_t u = __float_as_uint(f);
    uint_t r = (u + 0x7FFFu + ((u >> 16) & 1u)) >> 16;
    return (ushort_t)r;
}
static __device__ inline uint_t pack2bf(float x, float y) {
    return (uint_t)f2bf(x) | ((uint_t)f2bf(y) << 16);
}
static __device__ inline float bflo(uint_t v) { return __uint_as_float(v << 16); }
static __device__ inline float bfhi(uint_t v) { return __uint_as_float(v & 0xFFFF0000u); }

// ---- fused prep: CSR fill (node-major) + x->bf16 slice-major + weight transpose ----
// blocks [0,6250): edge fill;  [6250,12500): x2bf;  [12500,12692): wt3

__global__ __launch_bounds__(256) void k_prep(const int* __restrict__ src, const int* __restrict__ dst,
                                              int* __restrict__ cnt, int* __restrict__ col,
                                              const float* __restrict__ x, uint_t* __restrict__ xbs,
                                              const float* __restrict__ W1, const float* __restrict__ W2,
                                              const float* __restrict__ W3, ushort_t* __restrict__ WT) {
    int b = blockIdx.x;
    if (b < 6250) {
        int e = b * 256 + threadIdx.x;            // 1.6M exactly
        int d = dst[e];
        int p = atomicAdd(&cnt[d], 1);
        if (p < CAP) col[(size_t)d * CAP + p] = src[e];
    } else if (b < 12500) {
        int i = (b - 6250) * 256 + threadIdx.x;   // 1.6M threads x 8 floats
        int n = i >> 4, u16 = i & 15;             // u16 indexes a ushort8 (8 channels)
        const float4* xp = (const float4*)(x + (size_t)n * 128 + u16 * 8);
        float4 a = xp[0], bb = xp[1];
        uint4 o;
        o.x = pack2bf(a.x, a.y);
        o.y = pack2bf(a.z, a.w);
        o.z = pack2bf(bb.x, bb.y);
        o.w = pack2bf(bb.z, bb.w);
        int plane = u16 >> 1;                     // channel slice 0..7
        *(uint4*)(xbs + (size_t)plane * PLANE_U32 + n * 8 + (u16 & 1) * 4) = o;
    } else {
        int idx = (b - 12500) * 256 + threadIdx.x;  // 49152
        int w = idx >> 14;
        int r = idx & 16383;
        const float* W = (w == 0) ? W1 : (w == 1) ? W2 : W3;
        int k = r >> 7, n = r & 127;
        WT[w * 16384 + n * 128 + k] = f2bf(W[r]);
    }
}

// ---- slice-partitioned aggregate: zs[s][n] = hs[s][n] + sum_nbr hs[s][c] ----
// bid&7 = slice (XCD-local under round-robin); plane is L2-resident (3.2 MB).
// wave = 8 groups x 8 lanes; group g handles neighbor j = i*8+g-1 (j==-1 -> self).

__global__ __launch_bounds__(256) void k_agg(const uint_t* __restrict__ hin,
                                             const int* __restrict__ cnt,
                                             const int* __restrict__ col,
                                             uint_t* __restrict__ zout) {
    int bid = blockIdx.x;                 // 1568 = 8 slices x 196 blocks
    int s = bid & 7;
    int chunk = bid >> 3;                 // 0..195
    int w = threadIdx.x >> 6, lane = threadIdx.x & 63;
    int g = lane >> 3, m = lane & 7;
    int wc = chunk * 4 + w;               // 0..783
    int n0 = wc * 128;
    int n1 = n0 + 128; if (n1 > N_NODES) n1 = N_NODES;
    if (n0 >= N_NODES) return;

    const uint_t* __restrict__ hsu = hin + (size_t)s * PLANE_U32;
    uint_t* __restrict__ zsu = zout + (size_t)s * PLANE_U32;

    int e = cnt[n0]; if (e > CAP) e = CAP;
    int creg = (lane < e) ? col[(size_t)n0 * CAP + lane] : 0;

    for (int n = n0; n < n1; ++n) {
        // prefetch next node's degree + neighbor list
        int en = 0, cregn = 0;
        if (n + 1 < n1) {
            en = cnt[n + 1]; if (en > CAP) en = CAP;
            if (lane < en) cregn = col[(size_t)(n + 1) * CAP + lane];
        }

        float ax = 0.f, ay = 0.f;
        // items j = -1 (self) .. e-1 (neighbors); group g takes j = i*8+g-1
        for (int i = 0; i * 8 < e + 1; ++i) {
            int j = i * 8 + g - 1;
            int c = __shfl(creg, j & 63);
            if (j < 0) c = n;
            if (j < e) {
                uint_t v = hsu[(size_t)c * 8 + m];
                ax += bflo(v); ay += bfhi(v);
            }
        }
        // reduce across the 8 groups (lanes differing in bits 3..5)
        ax += __shfl_xor(ax, 8);  ay += __shfl_xor(ay, 8);
        ax += __shfl_xor(ax, 16); ay += __shfl_xor(ay, 16);
        ax += __shfl_xor(ax, 32); ay += __shfl_xor(ay, 32);
        if (g == 0) zsu[(size_t)n * 8 + m] = pack2bf(ax, ay);

        e = en; creg = cregn;
    }
}

// ---- GEMM: H = relu(Z @ W + b); Z,H slice-major bf16, fp32 acc, MFMA ----

__global__ __launch_bounds__(256) void k_gemm(const ushort_t* __restrict__ Zs,
                                              const ushort_t* __restrict__ WT,
                                              const float* __restrict__ bias,
                                              ushort_t* __restrict__ Hs) {
    __shared__ ushort_t ldsW[128 * 136];
    int tid = threadIdx.x;
    for (int i = tid; i < 2048; i += 256) {
        int r = i >> 4, c = i & 15;
        *(uint4*)(ldsW + r * 136 + c * 8) = *(const uint4*)(WT + r * 128 + c * 8);
    }
    __syncthreads();

    int wid = blockIdx.x * 4 + (tid >> 6);
    if (wid >= (N_NODES / 16)) return;
    int lane = tid & 63;
    int row0 = wid * 16;
    int mrow = row0 + (lane & 15);
    int kbase = (lane >> 4) * 8;

    f32x4 acc[8];
    #pragma unroll
    for (int nt = 0; nt < 8; ++nt) { f32x4 zz = {0.f, 0.f, 0.f, 0.f}; acc[nt] = zz; }

    #pragma unroll
    for (int kc = 0; kc < 4; ++kc) {
        int k0 = kc * 32 + kbase;
        // slice-major A fragment: plane = k0>>4, 8 consecutive k within the 32B slice
        bf16x8 afrag = *(const bf16x8*)(Zs + (size_t)(k0 >> 4) * PLANE_U16 + mrow * 16 + (k0 & 15));
        #pragma unroll
        for (int nt = 0; nt < 8; ++nt) {
            bf16x8 bfrag = *(const bf16x8*)(ldsW + (nt * 16 + (lane & 15)) * 136 + k0);
            acc[nt] = __builtin_amdgcn_mfma_f32_16x16x32_bf16(afrag, bfrag, acc[nt], 0, 0, 0);
        }
    }

    int colbase = lane & 15;
    int rsel = (lane >> 4) * 4;
    #pragma unroll
    for (int nt = 0; nt < 8; ++nt) {
        int coln = nt * 16 + colbase;      // plane = nt, in-slice ch = colbase
        float bv = bias[coln];
        #pragma unroll
        for (int r = 0; r < 4; ++r) {
            int grow = row0 + rsel + r;
            float v = fmaxf(acc[nt][r] + bv, 0.0f);
            Hs[(size_t)nt * PLANE_U16 + grow * 16 + colbase] = f2bf(v);
        }
    }
}

// ---- fused global mean pool + final linear (H slice-major) ----

__global__ __launch_bounds__(256) void k_poolfinal(const ushort_t* __restrict__ H,
                                                   const int* __restrict__ batch,
                                                   const float* __restrict__ Wf,
                                                   const float* __restrict__ bfv,
                                                   float* __restrict__ out) {
    __shared__ float sx[4][64];
    __shared__ float sy[4][64];
    __shared__ float pooled[128];
    int g = blockIdx.x;
    int t = threadIdx.x;
    int ch2 = t & 63;     // uint index: channels 2*ch2, 2*ch2+1
    int part = t >> 6;
    int lo = 0, hi = N_NODES;
    while (lo < hi) { int mid = (lo + hi) >> 1; if (batch[mid] < g) lo = mid + 1; else hi = mid; }
    int s = lo;
    lo = 0; hi = N_NODES;
    while (lo < hi) { int mid = (lo + hi) >> 1; if (batch[mid] < g + 1) lo = mid + 1; else hi = mid; }
    int e = lo;
    const uint_t* __restrict__ hp = (const uint_t*)H;
    const uint_t* __restrict__ hplane = hp + (size_t)(ch2 >> 3) * PLANE_U32;
    int moff = ch2 & 7;
    float ax = 0.f, ay = 0.f;
    for (int i = s + part; i < e; i += 4) {
        uint_t v = hplane[(size_t)i * 8 + moff];
        ax += bflo(v); ay += bfhi(v);
    }
    sx[part][ch2] = ax;
    sy[part][ch2] = ay;
    __syncthreads();
    if (t < 64) {
        float fx = sx[0][t] + sx[1][t] + sx[2][t] + sx[3][t];
        float fy = sy[0][t] + sy[1][t] + sy[2][t] + sy[3][t];
        float inv = 1.0f / fmaxf((float)(e - s), 1.0f);
        pooled[t * 2]     = fx * inv;
        pooled[t * 2 + 1] = fy * inv;
    }
    __syncthreads();
    if (t < 64) {
        float acc = bfv[t];
        #pragma unroll 8
        for (int k = 0; k < CH; ++k) acc += pooled[k] * Wf[k * 64 + t];
        out[g * 64 + t] = acc;
    }
}

extern "C" void kernel_launch(void* const* d_in, const int* in_sizes, int n_in,
                              void* d_out, int out_size, void* d_ws, size_t ws_size,
                              hipStream_t stream) {
    const float* x   = (const float*)d_in[0];
    const int*   ei  = (const int*)d_in[1];
    const int*   src = ei;
    const int*   dst = ei + N_EDGES;
    const int*   batch = (const int*)d_in[2];
    const float* W1 = (const float*)d_in[3];
    const float* b1 = (const float*)d_in[4];
    const float* W2 = (const float*)d_in[5];
    const float* b2 = (const float*)d_in[6];
    const float* W3 = (const float*)d_in[7];
    const float* b3 = (const float*)d_in[8];
    const float* Wf = (const float*)d_in[9];
    const float* bf = (const float*)d_in[10];
    float* out = (float*)d_out;

    char* p = (char*)d_ws;
    auto alloc = [&](size_t bytes) -> void* {
        void* r = (void*)p;
        p += (bytes + 255) & ~(size_t)255;
        return r;
    };
    int* cnt = (int*)alloc(N_NODES * sizeof(int));
    int* col = (int*)alloc((size_t)N_NODES * CAP * sizeof(int));    // node-major, 25.6 MB
    ushort_t* wt = (ushort_t*)alloc(3 * CH * CH * sizeof(ushort_t));
    uint_t* xb = (uint_t*)alloc((size_t)8 * PLANE_U32 * sizeof(uint_t));   // slice-major
    uint_t* za = (uint_t*)alloc((size_t)8 * PLANE_U32 * sizeof(uint_t));
    uint_t* ha = (uint_t*)alloc((size_t)8 * PLANE_U32 * sizeof(uint_t));

    hipMemsetAsync(cnt, 0, N_NODES * sizeof(int), stream);
    k_prep<<<12692, 256, 0, stream>>>(src, dst, cnt, col, x, xb, W1, W2, W3, wt);

    const int aggGrid  = 1568;                    // 8 slices x 196 blocks
    const int gemmGrid = (N_NODES / 16 + 3) / 4;  // 1563

    // layer 1: xb -> za -> ha
    k_agg<<<aggGrid, 256, 0, stream>>>(xb, cnt, col, za);
    k_gemm<<<gemmGrid, 256, 0, stream>>>((const ushort_t*)za, wt, b1, (ushort_t*)ha);
    // layer 2: ha -> za -> xb (reuse as h2)
    k_agg<<<aggGrid, 256, 0, stream>>>(ha, cnt, col, za);
    k_gemm<<<gemmGrid, 256, 0, stream>>>((const ushort_t*)za, wt + 16384, b2, (ushort_t*)xb);
    // layer 3: xb -> za -> ha
    k_agg<<<aggGrid, 256, 0, stream>>>(xb, cnt, col, za);
    k_gemm<<<gemmGrid, 256, 0, stream>>>((const ushort_t*)za, wt + 32768, b3, (ushort_t*)ha);

    k_poolfinal<<<N_GRAPHS, 256, 0, stream>>>((const ushort_t*)ha, batch, Wf, bf, out);
}

// Round 6
// 390.274 us; speedup vs baseline: 2.4774x; 2.4774x over previous
//
#include <hip/hip_runtime.h>

#define N_NODES 100000
#define N_EDGES 1600000
#define N_GRAPHS 256
#define CH 128
#define OUT_CH 64
#define NB 391        // dst buckets of 256 nodes (391*256 = 100096)
#define BCAP 4608     // edge capacity per bucket (mean 4092 + 8 sigma)
#define CAPN 48       // per-node neighbor capacity (max degree ~38 for this graph)

typedef __attribute__((ext_vector_type(8))) short bf16x8;
typedef __attribute__((ext_vector_type(4))) float f32x4;
typedef unsigned short ushort_t;
typedef unsigned int uint_t;

static __device__ inline ushort_t f2bf(float f) {
    uint_t u = __float_as_uint(f);
    uint_t r = (u + 0x7FFFu + ((u >> 16) & 1u)) >> 16;
    return (ushort_t)r;
}
static __device__ inline uint_t pack2bf(float x, float y) {
    return (uint_t)f2bf(x) | ((uint_t)f2bf(y) << 16);
}
static __device__ inline float bflo(uint_t v) { return __uint_as_float(v << 16); }
static __device__ inline float bfhi(uint_t v) { return __uint_as_float(v & 0xFFFF0000u); }

// ---- pass A: bucket-partition edges (packed uint) + x->bf16 + weight transpose ----
// blocks [0,196): edge partition; [196,1759): x2bf; [1759,1807): wt3

__global__ __launch_bounds__(1024) void k_passA(const int* __restrict__ src, const int* __restrict__ dst,
                                                int* __restrict__ resCnt, uint_t* __restrict__ pairBuf,
                                                const float* __restrict__ x, ushort_t* __restrict__ xb,
                                                const float* __restrict__ W1, const float* __restrict__ W2,
                                                const float* __restrict__ W3, ushort_t* __restrict__ WT) {
    int blk = blockIdx.x, tid = threadIdx.x;
    if (blk < 196) {
        __shared__ int hist[NB];
        __shared__ int base[NB];
        for (int t = tid; t < NB; t += 1024) hist[t] = 0;
        __syncthreads();
        uint_t v[8]; int bk[8], rk[8];
        int e0 = blk * 8192;
        #pragma unroll
        for (int j = 0; j < 8; ++j) {
            int e = e0 + j * 1024 + tid;
            bk[j] = -1;
            if (e < N_EDGES) {
                int d = dst[e];
                int s = src[e];
                int b = d >> 8;
                bk[j] = b;
                v[j] = (uint_t)s | ((uint_t)(d & 255) << 17);
                rk[j] = atomicAdd(&hist[b], 1);
            }
        }
        __syncthreads();
        for (int t = tid; t < NB; t += 1024)
            base[t] = atomicAdd(&resCnt[t * 16], hist[t]);   // padded: 1 counter per line
        __syncthreads();
        #pragma unroll
        for (int j = 0; j < 8; ++j) {
            if (bk[j] >= 0) {
                int pos = base[bk[j]] + rk[j];
                if (pos < BCAP) pairBuf[(size_t)bk[j] * BCAP + pos] = v[j];
            }
        }
    } else if (blk < 1759) {
        int i = (blk - 196) * 1024 + tid;    // 1.6M ushort8 units
        if (i < N_NODES * 16) {
            const float4* xp = (const float4*)(x) + (size_t)i * 2;
            float4 a = xp[0], bb = xp[1];
            uint4 o;
            o.x = pack2bf(a.x, a.y);
            o.y = pack2bf(a.z, a.w);
            o.z = pack2bf(bb.x, bb.y);
            o.w = pack2bf(bb.z, bb.w);
            ((uint4*)xb)[i] = o;
        }
    } else {
        int idx = (blk - 1759) * 1024 + tid;  // 49152 exactly
        int w = idx >> 14;
        int r = idx & 16383;
        const float* W = (w == 0) ? W1 : (w == 1) ? W2 : W3;
        int k = r >> 7, n = r & 127;
        WT[w * 16384 + n * 128 + k] = f2bf(W[r]);
    }
}

// ---- pass B: per-bucket CSR in LDS, fully-coalesced writeback ----

__global__ __launch_bounds__(256) void k_passB(const int* __restrict__ resCnt,
                                               const uint_t* __restrict__ pairBuf,
                                               int* __restrict__ cnt, int* __restrict__ col) {
    __shared__ int csr[256 * CAPN];   // 48 KB
    __shared__ int lcnt[256];
    int b = blockIdx.x, tid = threadIdx.x;
    lcnt[tid] = 0;
    for (int i = tid; i < 256 * CAPN; i += 256) csr[i] = 0;   // determinism for unused slots
    __syncthreads();
    int ce = resCnt[b * 16];
    if (ce > BCAP) ce = BCAP;
    const uint_t* __restrict__ pb = pairBuf + (size_t)b * BCAP;
    for (int i = tid; i < ce; i += 256) {
        uint_t v = pb[i];
        int d = v >> 17;
        int p = atomicAdd(&lcnt[d], 1);
        if (p < CAPN) csr[d * CAPN + p] = (int)(v & 0x1FFFFu);
    }
    __syncthreads();
    int gbase = b * 256;
    int lim = (gbase + 256 <= N_NODES) ? 256 * CAPN : (N_NODES - gbase) * CAPN;
    for (int i = tid; i < lim; i += 256) col[(size_t)gbase * CAPN + i] = csr[i];
    int node = gbase + tid;
    if (node < N_NODES) {
        int c = lcnt[tid];
        cnt[node] = c > CAPN ? CAPN : c;
    }
}

// ---- aggregate: z[i] = h[i] + sum_nbr h[j]  (bf16 node-major, fp32 acc) ----

__global__ __launch_bounds__(256) void k_agg(const ushort_t* __restrict__ hin,
                                             const int* __restrict__ cnt,
                                             const int* __restrict__ col,
                                             ushort_t* __restrict__ zout) {
    int bid = blockIdx.x;                 // 25000 = 8 * 3125, XCD swizzle
    int group = (bid & 7) * 3125 + (bid >> 3);
    int node = group * 4 + (threadIdx.x >> 6);   // < 100000 exactly
    int lane = threadIdx.x & 63;
    const uint_t* __restrict__ hp = (const uint_t*)hin;

    int e = cnt[node];                            // already clamped <= CAPN
    int creg = (lane < CAPN) ? col[(size_t)node * CAPN + lane] : 0;

    uint_t sv = hp[(size_t)node * 64 + lane];
    float a0x = bflo(sv), a0y = bfhi(sv);
    float a1x = 0.f, a1y = 0.f, a2x = 0.f, a2y = 0.f, a3x = 0.f, a3y = 0.f;

    int i = 0;
    for (; i + 3 < e; i += 4) {
        int c0 = __shfl(creg, i);
        int c1 = __shfl(creg, i + 1);
        int c2 = __shfl(creg, i + 2);
        int c3 = __shfl(creg, i + 3);
        uint_t v0 = hp[(size_t)c0 * 64 + lane];
        uint_t v1 = hp[(size_t)c1 * 64 + lane];
        uint_t v2 = hp[(size_t)c2 * 64 + lane];
        uint_t v3 = hp[(size_t)c3 * 64 + lane];
        a0x += bflo(v0); a0y += bfhi(v0);
        a1x += bflo(v1); a1y += bfhi(v1);
        a2x += bflo(v2); a2y += bfhi(v2);
        a3x += bflo(v3); a3y += bfhi(v3);
    }
    for (; i < e; ++i) {
        int c = __shfl(creg, i);
        uint_t v = hp[(size_t)c * 64 + lane];
        a0x += bflo(v); a0y += bfhi(v);
    }
    float rx = (a0x + a1x) + (a2x + a3x);
    float ry = (a0y + a1y) + (a2y + a3y);
    ((uint_t*)zout)[(size_t)node * 64 + lane] = pack2bf(rx, ry);
}

// ---- GEMM: H = relu(Z @ W + b), bf16 node-major in/out, fp32 acc, MFMA ----

__global__ __launch_bounds__(256) void k_gemm(const ushort_t* __restrict__ Zb,
                                              const ushort_t* __restrict__ WT,
                                              const float* __restrict__ bias,
                                              ushort_t* __restrict__ H) {
    __shared__ ushort_t ldsW[128 * 136];
    int tid = threadIdx.x;
    for (int i = tid; i < 2048; i += 256) {
        int r = i >> 4, c = i & 15;
        *(uint4*)(ldsW + r * 136 + c * 8) = *(const uint4*)(WT + r * 128 + c * 8);
    }
    __syncthreads();

    int wid = blockIdx.x * 4 + (tid >> 6);
    if (wid >= (N_NODES / 16)) return;
    int lane = tid & 63;
    int row0 = wid * 16;
    int mrow = row0 + (lane & 15);
    int kbase = (lane >> 4) * 8;

    f32x4 acc[8];
    #pragma unroll
    for (int nt = 0; nt < 8; ++nt) { f32x4 zz = {0.f, 0.f, 0.f, 0.f}; acc[nt] = zz; }

    #pragma unroll
    for (int kc = 0; kc < 4; ++kc) {
        int k0 = kc * 32 + kbase;
        bf16x8 afrag = *(const bf16x8*)(Zb + (size_t)mrow * 128 + k0);
        #pragma unroll
        for (int nt = 0; nt < 8; ++nt) {
            bf16x8 bfrag = *(const bf16x8*)(ldsW + (nt * 16 + (lane & 15)) * 136 + k0);
            acc[nt] = __builtin_amdgcn_mfma_f32_16x16x32_bf16(afrag, bfrag, acc[nt], 0, 0, 0);
        }
    }

    int colbase = lane & 15;
    int rsel = (lane >> 4) * 4;
    #pragma unroll
    for (int nt = 0; nt < 8; ++nt) {
        int coln = nt * 16 + colbase;
        float bv = bias[coln];
        #pragma unroll
        for (int r = 0; r < 4; ++r) {
            int grow = row0 + rsel + r;
            float v = fmaxf(acc[nt][r] + bv, 0.0f);
            H[(size_t)grow * 128 + coln] = f2bf(v);
        }
    }
}

// ---- fused global mean pool + final linear ----

__global__ __launch_bounds__(256) void k_poolfinal(const ushort_t* __restrict__ H,
                                                   const int* __restrict__ batch,
                                                   const float* __restrict__ Wf,
                                                   const float* __restrict__ bfv,
                                                   float* __restrict__ out) {
    __shared__ float sx[4][64];
    __shared__ float sy[4][64];
    __shared__ float pooled[128];
    int g = blockIdx.x;
    int t = threadIdx.x;
    int ch2 = t & 63;
    int part = t >> 6;
    int lo = 0, hi = N_NODES;
    while (lo < hi) { int mid = (lo + hi) >> 1; if (batch[mid] < g) lo = mid + 1; else hi = mid; }
    int s = lo;
    lo = 0; hi = N_NODES;
    while (lo < hi) { int mid = (lo + hi) >> 1; if (batch[mid] < g + 1) lo = mid + 1; else hi = mid; }
    int e = lo;
    const uint_t* __restrict__ hp = (const uint_t*)H;
    float ax = 0.f, ay = 0.f;
    for (int i = s + part; i < e; i += 4) {
        uint_t v = hp[(size_t)i * 64 + ch2];
        ax += bflo(v); ay += bfhi(v);
    }
    sx[part][ch2] = ax;
    sy[part][ch2] = ay;
    __syncthreads();
    if (t < 64) {
        float fx = sx[0][t] + sx[1][t] + sx[2][t] + sx[3][t];
        float fy = sy[0][t] + sy[1][t] + sy[2][t] + sy[3][t];
        float inv = 1.0f / fmaxf((float)(e - s), 1.0f);
        pooled[t * 2]     = fx * inv;
        pooled[t * 2 + 1] = fy * inv;
    }
    __syncthreads();
    if (t < 64) {
        float acc = bfv[t];
        #pragma unroll 8
        for (int k = 0; k < CH; ++k) acc += pooled[k] * Wf[k * 64 + t];
        out[g * 64 + t] = acc;
    }
}

extern "C" void kernel_launch(void* const* d_in, const int* in_sizes, int n_in,
                              void* d_out, int out_size, void* d_ws, size_t ws_size,
                              hipStream_t stream) {
    const float* x   = (const float*)d_in[0];
    const int*   ei  = (const int*)d_in[1];
    const int*   src = ei;
    const int*   dst = ei + N_EDGES;
    const int*   batch = (const int*)d_in[2];
    const float* W1 = (const float*)d_in[3];
    const float* b1 = (const float*)d_in[4];
    const float* W2 = (const float*)d_in[5];
    const float* b2 = (const float*)d_in[6];
    const float* W3 = (const float*)d_in[7];
    const float* b3 = (const float*)d_in[8];
    const float* Wf = (const float*)d_in[9];
    const float* bf = (const float*)d_in[10];
    float* out = (float*)d_out;

    char* p = (char*)d_ws;
    auto alloc = [&](size_t bytes) -> void* {
        void* r = (void*)p;
        p += (bytes + 255) & ~(size_t)255;
        return r;
    };
    int* resCnt = (int*)alloc((size_t)NB * 16 * sizeof(int));            // 25 KB, padded
    uint_t* pairBuf = (uint_t*)alloc((size_t)NB * BCAP * sizeof(uint_t)); // 7.2 MB
    int* cnt = (int*)alloc(N_NODES * sizeof(int));
    int* col = (int*)alloc((size_t)(NB * 256) * CAPN * sizeof(int));      // 19.2 MB node-major
    ushort_t* wt = (ushort_t*)alloc(3 * CH * CH * sizeof(ushort_t));
    ushort_t* xb = (ushort_t*)alloc((size_t)N_NODES * CH * sizeof(ushort_t));
    ushort_t* z  = (ushort_t*)alloc((size_t)N_NODES * CH * sizeof(ushort_t));
    ushort_t* ha = (ushort_t*)alloc((size_t)N_NODES * CH * sizeof(ushort_t));
    ushort_t* hb = (ushort_t*)alloc((size_t)N_NODES * CH * sizeof(ushort_t));

    hipMemsetAsync(resCnt, 0, (size_t)NB * 16 * sizeof(int), stream);
    k_passA<<<1807, 1024, 0, stream>>>(src, dst, resCnt, pairBuf, x, xb, W1, W2, W3, wt);
    k_passB<<<NB, 256, 0, stream>>>(resCnt, pairBuf, cnt, col);

    const int aggGrid  = 25000;                   // 4 nodes/block, XCD swizzle
    const int gemmGrid = (N_NODES / 16 + 3) / 4;  // 1563

    k_agg<<<aggGrid, 256, 0, stream>>>(xb, cnt, col, z);
    k_gemm<<<gemmGrid, 256, 0, stream>>>(z, wt, b1, ha);
    k_agg<<<aggGrid, 256, 0, stream>>>(ha, cnt, col, z);
    k_gemm<<<gemmGrid, 256, 0, stream>>>(z, wt + 16384, b2, hb);
    k_agg<<<aggGrid, 256, 0, stream>>>(hb, cnt, col, z);
    k_gemm<<<gemmGrid, 256, 0, stream>>>(z, wt + 32768, b3, ha);

    k_poolfinal<<<N_GRAPHS, 256, 0, stream>>>(ha, batch, Wf, bf, out);
}